// Round 1
// baseline (102.600 us; speedup 1.0000x reference)
//
#include <hip/hip_runtime.h>
#include <math.h>

constexpr int Bn = 64, Sn = 6, Tn = 2000, Cn = 25;
constexpr int COLS = Sn * Tn;              // 12000
constexpr int ROWS = Bn * Sn * Tn;         // 768000
constexpr int BDIM = 256;
constexpr int RPB  = 256;                  // rows per fret block
constexpr int FBLK = ROWS / RPB;           // 3000 fret blocks (exact)
constexpr int FPAD = 3072;                 // padded leading dim for pf
constexpr int OBLK = (COLS + BDIM - 1) / BDIM;  // 47 onset blocks
constexpr int OPAD = 64;
constexpr int GRID = FBLK + OBLK;          // 3047

// Cross-block state in device globals (zero-initialized once at module load;
// NOT re-poisoned by the harness). Ticket is monotonic: last block of each
// launch sees old % GRID == GRID-1, so no per-launch reset is needed.
__device__ float    g_pf[Sn * FPAD];
__device__ float    g_po[Sn * OPAD];
__device__ unsigned g_ticket = 0;

static __device__ __forceinline__ float agent_load(const float* p) {
    return __hip_atomic_load(p, __ATOMIC_RELAXED, __HIP_MEMORY_SCOPE_AGENT);
}
static __device__ __forceinline__ void agent_store(float* p, float v) {
    __hip_atomic_store(p, v, __ATOMIC_RELAXED, __HIP_MEMORY_SCOPE_AGENT);
}

// Segmented (<=2 strings per wave) butterfly reduce + LDS accumulate.
static __device__ __forceinline__ void seg_reduce_add(float* ls, int s, float v, int lane) {
    const int s0 = __shfl(s, 0, 64);
    const int s1 = __shfl(s, 63, 64);
    if (s0 == s1) {                         // wave-uniform branch
        float a = v;
        #pragma unroll
        for (int off = 32; off; off >>= 1) a += __shfl_xor(a, off, 64);
        if (lane == 0) atomicAdd(&ls[s0], a);
    } else {
        float a = (s == s0) ? v : 0.0f;
        float b = (s == s0) ? 0.0f : v;
        #pragma unroll
        for (int off = 32; off; off >>= 1) {
            a += __shfl_xor(a, off, 64);
            b += __shfl_xor(b, off, 64);
        }
        if (lane == 0) { atomicAdd(&ls[s0], a); atomicAdd(&ls[s1], b); }
    }
}

__global__ __launch_bounds__(BDIM) void main_kernel(const float4* __restrict__ x4,
                                                    const int*    __restrict__ tgt,
                                                    const float*  __restrict__ ox,
                                                    const float*  __restrict__ ot,
                                                    float* __restrict__ out) {
    __shared__ float lds[RPB * Cn];        // 25.6 KB row stage (fret path only)
    __shared__ float ls[Sn];
    __shared__ float accf[Sn], acco[Sn];
    __shared__ int   amLast;
    const int tid  = threadIdx.x;
    const int lane = tid & 63;
    if (tid < Sn) ls[tid] = 0.0f;

    if (blockIdx.x < OBLK) {
        // ---------------- onset path: softmax over B per column ----------------
        __syncthreads();
        const int col = blockIdx.x * BDIM + tid;
        float on = 0.0f;
        int   s  = Sn - 1;                  // safe string for invalid tail lanes
        if (col < COLS) {
            s = col / Tn;
            float M = -INFINITY, S = 0.0f, ts = 0.0f, txs = 0.0f;
            for (int b0 = 0; b0 < Bn; b0 += 16) {
                float xv[16];
                #pragma unroll
                for (int k = 0; k < 16; ++k) xv[k] = ox[(b0 + k) * COLS + col];
                #pragma unroll
                for (int k = 0; k < 16; ++k) {
                    const float tv = ot[(b0 + k) * COLS + col];
                    ts  += tv;
                    txs += tv * xv[k];
                }
                float cm = -INFINITY;
                #pragma unroll
                for (int k = 0; k < 16; ++k) cm = fmaxf(cm, xv[k]);
                float cs = 0.0f;
                #pragma unroll
                for (int k = 0; k < 16; ++k) cs += __expf(xv[k] - cm);
                const float nm = fmaxf(M, cm);
                S = S * __expf(M - nm) + cs * __expf(cm - nm);   // exp(-inf)=0 first iter
                M = nm;
            }
            on = ts * (M + __logf(S)) - txs;
        }
        seg_reduce_add(ls, s, on, lane);
        __syncthreads();
        if (tid < Sn) agent_store(&g_po[tid * OPAD + blockIdx.x], ls[tid]);
    } else {
        // ---------------- fret path: CE over 25 classes per row ----------------
        const int fb   = blockIdx.x - OBLK;
        const int row  = fb * RPB + tid;
        const int tcls = tgt[row];          // prefetched: overlaps staging
        const float4* src = x4 + (long)fb * (RPB * Cn / 4);
        float4* lds4 = (float4*)lds;
        for (int k = tid; k < RPB * Cn / 4; k += BDIM) lds4[k] = src[k];
        __syncthreads();

        const float* myrow = lds + tid * Cn;   // stride 25: free 2-way aliasing
        float m = -INFINITY;
        #pragma unroll
        for (int c = 0; c < Cn; ++c) m = fmaxf(m, myrow[c]);
        float sum = 0.0f;
        #pragma unroll
        for (int c = 0; c < Cn; ++c) sum += __expf(myrow[c] - m);
        const float nll = m + __logf(sum) - myrow[tcls];

        const int s = (row / Tn) % Sn;
        seg_reduce_add(ls, s, nll, lane);   // replaces 64-way same-address LDS atomic
        __syncthreads();
        if (tid < Sn) agent_store(&g_pf[tid * FPAD + fb], ls[tid]);
    }

    // ---------------- last-block-done fused finish ----------------
    __syncthreads();                        // drains this block's partial stores (vmcnt 0)
    if (tid == 0) {
        const unsigned old = __hip_atomic_fetch_add(&g_ticket, 1u, __ATOMIC_ACQ_REL,
                                                    __HIP_MEMORY_SCOPE_AGENT);
        amLast = ((old % (unsigned)GRID) == (unsigned)(GRID - 1)) ? 1 : 0;
    }
    __syncthreads();
    if (amLast) {
        if (tid < Sn) { accf[tid] = 0.0f; acco[tid] = 0.0f; }
        __syncthreads();
        float fs[Sn], os[Sn];
        #pragma unroll
        for (int s = 0; s < Sn; ++s) {
            float v = 0.0f;
            for (int i = tid; i < FBLK; i += BDIM)      // 12 coalesced loads/thread
                v += agent_load(&g_pf[s * FPAD + i]);
            fs[s] = v;
            float w = 0.0f;
            for (int i = tid; i < OBLK; i += BDIM)
                w += agent_load(&g_po[s * OPAD + i]);
            os[s] = w;
        }
        #pragma unroll
        for (int off = 32; off; off >>= 1) {
            #pragma unroll
            for (int s = 0; s < Sn; ++s) {
                fs[s] += __shfl_xor(fs[s], off, 64);
                os[s] += __shfl_xor(os[s], off, 64);
            }
        }
        if (lane == 0) {
            #pragma unroll
            for (int s = 0; s < Sn; ++s) { atomicAdd(&accf[s], fs[s]); atomicAdd(&acco[s], os[s]); }
        }
        __syncthreads();
        if (tid == 0) {
            float fret = 0.0f, onv = 0.0f, fsv[Sn], osv[Sn];
            #pragma unroll
            for (int s = 0; s < Sn; ++s) {
                fsv[s] = accf[s] * (1.0f / Bn);         // mean over batch
                osv[s] = acco[s];
                fret += fsv[s];
                onv  += osv[s];
            }
            out[0] = 0.5f * fret + 0.5f * onv;          // WEIGHT_FRET_ONSET = 0.5
            out[1] = fret;
            out[2] = onv;
            #pragma unroll
            for (int s = 0; s < Sn; ++s) { out[3 + s] = fsv[s]; out[9 + s] = osv[s]; }
        }
    }
}

extern "C" void kernel_launch(void* const* d_in, const int* in_sizes, int n_in,
                              void* d_out, int out_size, void* d_ws, size_t ws_size,
                              hipStream_t stream) {
    const float* output_fret  = (const float*)d_in[0];
    const int*   target_fret  = (const int*)d_in[1];
    const float* output_onset = (const float*)d_in[2];
    const float* target_onset = (const float*)d_in[3];
    float* out = (float*)d_out;
    (void)d_ws; (void)ws_size;

    main_kernel<<<GRID, BDIM, 0, stream>>>((const float4*)output_fret, target_fret,
                                           output_onset, target_onset, out);
}

// Round 2
// 69.707 us; speedup vs baseline: 1.4719x; 1.4719x over previous
//
#include <hip/hip_runtime.h>
#include <math.h>

constexpr int Bn = 64, Sn = 6, Tn = 2000, Cn = 25;
constexpr int COLS = Sn * Tn;              // 12000
constexpr int ROWS = Bn * Sn * Tn;         // 768000
constexpr int BDIM = 256;
constexpr int WV   = BDIM / 64;            // 4 waves per block
constexpr int RPB  = 256;                  // rows per fret block
constexpr int FBLK = ROWS / RPB;           // 3000 fret blocks (exact)
constexpr int FPAD = 3072;                 // padded leading dim for pf
constexpr int OBLK = (COLS + BDIM - 1) / BDIM;  // 47 onset blocks
constexpr int OPAD = 64;
constexpr int GRID = FBLK + OBLK;          // 3047

// Cross-block state in device globals (zero-initialized at module load, never
// re-poisoned). Ticket is monotonic: the last block of each launch sees
// old % GRID == GRID-1, so no per-launch reset and no graph-capture hazard.
__device__ float    g_pf[Sn * FPAD];
__device__ float    g_po[Sn * OPAD];
__device__ unsigned g_ticket = 0;

// Agent-scope RELAXED atomics: sc0/sc1-flagged ops that bypass the per-XCD L2
// to the coherence point. NO fences anywhere — ACQ_REL at agent scope emits
// buffer_wbl2/buffer_inv per block, which round 1 measured as a 3.7x kernel-
// wide stall (VALUBusy 4%, HBM 5%, dur 113us). Ordering of partial-store ->
// ticket-add is provided by __syncthreads() (compiler emits s_waitcnt vmcnt(0)
// before s_barrier), which is sufficient for cache-bypassing stores.
static __device__ __forceinline__ float agent_load(const float* p) {
    return __hip_atomic_load(p, __ATOMIC_RELAXED, __HIP_MEMORY_SCOPE_AGENT);
}
static __device__ __forceinline__ void agent_store(float* p, float v) {
    __hip_atomic_store(p, v, __ATOMIC_RELAXED, __HIP_MEMORY_SCOPE_AGENT);
}

// Segmented (<=2 contiguous strings per wave) butterfly reduce + LDS add.
static __device__ __forceinline__ void seg_reduce_add(float* ls, int s, float v, int lane) {
    const int s0 = __shfl(s, 0, 64);
    const int s1 = __shfl(s, 63, 64);
    if (s0 == s1) {                         // wave-uniform branch
        float a = v;
        #pragma unroll
        for (int off = 32; off; off >>= 1) a += __shfl_xor(a, off, 64);
        if (lane == 0) atomicAdd(&ls[s0], a);
    } else {
        float a = (s == s0) ? v : 0.0f;
        float b = (s == s0) ? 0.0f : v;
        #pragma unroll
        for (int off = 32; off; off >>= 1) {
            a += __shfl_xor(a, off, 64);
            b += __shfl_xor(b, off, 64);
        }
        if (lane == 0) { atomicAdd(&ls[s0], a); atomicAdd(&ls[s1], b); }
    }
}

__global__ __launch_bounds__(BDIM) void main_kernel(const float4* __restrict__ x4,
                                                    const int*    __restrict__ tgt,
                                                    const float*  __restrict__ ox,
                                                    const float*  __restrict__ ot,
                                                    float* __restrict__ out) {
    __shared__ float lds[RPB * Cn];        // 25.6 KB; wave w owns [w*64*Cn, +1600)
    __shared__ float ws[WV][Sn];           // per-wave string partials (no init race)
    __shared__ float accf[Sn], acco[Sn];
    __shared__ int   amLast;
    const int tid  = threadIdx.x;
    const int lane = tid & 63;
    const int w    = tid >> 6;
    if (lane < Sn) ws[w][lane] = 0.0f;     // same-wave ordering: no barrier needed

    if (blockIdx.x < OBLK) {
        // ---------------- onset path: softmax over B per column ----------------
        const int col = blockIdx.x * BDIM + tid;
        float on = 0.0f;
        int   s  = Sn - 1;                  // tail lanes: contiguity-safe string
        if (col < COLS) {
            s = col / Tn;
            float M = -INFINITY, S = 0.0f, ts = 0.0f, txs = 0.0f;
            for (int b0 = 0; b0 < Bn; b0 += 16) {
                float xv[16];
                #pragma unroll
                for (int k = 0; k < 16; ++k) xv[k] = ox[(b0 + k) * COLS + col];
                #pragma unroll
                for (int k = 0; k < 16; ++k) {
                    const float tv = ot[(b0 + k) * COLS + col];
                    ts  += tv;
                    txs += tv * xv[k];
                }
                float cm = -INFINITY;
                #pragma unroll
                for (int k = 0; k < 16; ++k) cm = fmaxf(cm, xv[k]);
                float cs = 0.0f;
                #pragma unroll
                for (int k = 0; k < 16; ++k) cs += __expf(xv[k] - cm);
                const float nm = fmaxf(M, cm);
                S = S * __expf(M - nm) + cs * __expf(cm - nm);   // exp(-inf)=0 first iter
                M = nm;
            }
            on = ts * (M + __logf(S)) - txs;
        }
        seg_reduce_add(ws[w], s, on, lane);
        __syncthreads();
        if (tid < Sn)
            agent_store(&g_po[tid * OPAD + blockIdx.x],
                        ws[0][tid] + ws[1][tid] + ws[2][tid] + ws[3][tid]);
    } else {
        // ---------------- fret path: CE over 25 classes per row ----------------
        const int fb   = blockIdx.x - OBLK;
        const int row  = fb * RPB + tid;
        const int tcls = tgt[row];          // prefetched: overlaps staging
        // Per-wave staging: each wave loads its own 64 rows (400 float4, 1KB/instr
        // coalesced) into its own LDS region -> NO inter-wave barrier in hot path.
        const float4* src = x4 + (long)fb * (RPB * Cn / 4) + w * (64 * Cn / 4);
        float4* dst = (float4*)(lds + w * 64 * Cn);
        for (int k = lane; k < 64 * Cn / 4; k += 64) dst[k] = src[k];

        const float* myrow = lds + tid * Cn;   // stride 25: free 2-way aliasing
        float m = -INFINITY;
        #pragma unroll
        for (int c = 0; c < Cn; ++c) m = fmaxf(m, myrow[c]);
        float sum = 0.0f;
        #pragma unroll
        for (int c = 0; c < Cn; ++c) sum += __expf(myrow[c] - m);
        const float nll = m + __logf(sum) - myrow[tcls];

        const int s = (row / Tn) % Sn;
        seg_reduce_add(ws[w], s, nll, lane);
        __syncthreads();
        if (tid < Sn)
            agent_store(&g_pf[tid * FPAD + fb],
                        ws[0][tid] + ws[1][tid] + ws[2][tid] + ws[3][tid]);
    }

    // ---------------- last-block-done fused finish (fence-free) ----------------
    __syncthreads();                        // s_waitcnt vmcnt(0): partials complete
    if (tid == 0) {
        const unsigned old = __hip_atomic_fetch_add(&g_ticket, 1u, __ATOMIC_RELAXED,
                                                    __HIP_MEMORY_SCOPE_AGENT);
        amLast = ((old % (unsigned)GRID) == (unsigned)(GRID - 1)) ? 1 : 0;
    }
    __syncthreads();
    if (amLast) {
        if (tid < Sn) { accf[tid] = 0.0f; acco[tid] = 0.0f; }
        __syncthreads();
        float fs[Sn], os[Sn];
        #pragma unroll
        for (int s = 0; s < Sn; ++s) {
            float v = 0.0f;
            for (int i = tid; i < FBLK; i += BDIM)      // 12 coalesced loads/thread
                v += agent_load(&g_pf[s * FPAD + i]);
            fs[s] = v;
            float u = 0.0f;
            for (int i = tid; i < OBLK; i += BDIM)
                u += agent_load(&g_po[s * OPAD + i]);
            os[s] = u;
        }
        #pragma unroll
        for (int off = 32; off; off >>= 1) {
            #pragma unroll
            for (int s = 0; s < Sn; ++s) {
                fs[s] += __shfl_xor(fs[s], off, 64);
                os[s] += __shfl_xor(os[s], off, 64);
            }
        }
        if (lane == 0) {
            #pragma unroll
            for (int s = 0; s < Sn; ++s) { atomicAdd(&accf[s], fs[s]); atomicAdd(&acco[s], os[s]); }
        }
        __syncthreads();
        if (tid == 0) {
            float fret = 0.0f, onv = 0.0f, fsv[Sn], osv[Sn];
            #pragma unroll
            for (int s = 0; s < Sn; ++s) {
                fsv[s] = accf[s] * (1.0f / Bn);         // mean over batch
                osv[s] = acco[s];
                fret += fsv[s];
                onv  += osv[s];
            }
            out[0] = 0.5f * fret + 0.5f * onv;          // WEIGHT_FRET_ONSET = 0.5
            out[1] = fret;
            out[2] = onv;
            #pragma unroll
            for (int s = 0; s < Sn; ++s) { out[3 + s] = fsv[s]; out[9 + s] = osv[s]; }
        }
    }
}

extern "C" void kernel_launch(void* const* d_in, const int* in_sizes, int n_in,
                              void* d_out, int out_size, void* d_ws, size_t ws_size,
                              hipStream_t stream) {
    const float* output_fret  = (const float*)d_in[0];
    const int*   target_fret  = (const int*)d_in[1];
    const float* output_onset = (const float*)d_in[2];
    const float* target_onset = (const float*)d_in[3];
    float* out = (float*)d_out;
    (void)d_ws; (void)ws_size;

    main_kernel<<<GRID, BDIM, 0, stream>>>((const float4*)output_fret, target_fret,
                                           output_onset, target_onset, out);
}

// Round 3
// 33.304 us; speedup vs baseline: 3.0807x; 2.0931x over previous
//
#include <hip/hip_runtime.h>
#include <math.h>

constexpr int Bn = 64, Sn = 6, Tn = 2000, Cn = 25;
constexpr int COLS = Sn * Tn;              // 12000
constexpr int ROWS = Bn * Sn * Tn;         // 768000
constexpr int BDIM = 256;
constexpr int WV   = BDIM / 64;            // 4 waves per block

constexpr int RPT  = 4;                    // rows per thread (fret), quad = 25 float4
constexpr int RPB  = BDIM * RPT;           // 1024 rows per block
constexpr int FBLK = ROWS / RPB;           // 750 fret blocks (exact)
constexpr int FPAD = 768;                  // padded leading dim for pf

constexpr int CPT  = 4;                    // cols per thread (onset), float4
constexpr int CQN  = COLS / CPT;           // 3000 col-quads
constexpr int OBLK = (CQN + BDIM - 1) / BDIM;   // 12 onset blocks
constexpr int OPAD = 16;
constexpr int GRID = OBLK + FBLK;          // 762

static __device__ __forceinline__ float comp(const float4& v, int j) {
    return j == 0 ? v.x : j == 1 ? v.y : j == 2 ? v.z : v.w;  // j is unroll-constant
}

// Segmented (<=2 contiguous strings per wave) butterfly reduce + LDS add.
static __device__ __forceinline__ void seg_reduce_add(float* ls, int s, float v, int lane) {
    const int s0 = __shfl(s, 0, 64);
    const int s1 = __shfl(s, 63, 64);
    if (s0 == s1) {                         // wave-uniform branch
        float a = v;
        #pragma unroll
        for (int off = 32; off; off >>= 1) a += __shfl_xor(a, off, 64);
        if (lane == 0) atomicAdd(&ls[s0], a);
    } else {
        float a = (s == s0) ? v : 0.0f;
        float b = (s == s0) ? 0.0f : v;
        #pragma unroll
        for (int off = 32; off; off >>= 1) {
            a += __shfl_xor(a, off, 64);
            b += __shfl_xor(b, off, 64);
        }
        if (lane == 0) { atomicAdd(&ls[s0], a); atomicAdd(&ls[s1], b); }
    }
}

// Register-direct main kernel: no LDS staging, no global ticket, plain stores
// to d_ws partials (kernel boundary provides coherence for the finish pass).
__global__ __launch_bounds__(BDIM, 2) void main_kernel(const float4* __restrict__ x4,
                                                       const int4*   __restrict__ tgt4,
                                                       const float*  __restrict__ ox,
                                                       const float*  __restrict__ ot,
                                                       float* __restrict__ pf,
                                                       float* __restrict__ po) {
    __shared__ float ws[WV][Sn];           // per-wave string partials
    const int tid  = threadIdx.x;
    const int lane = tid & 63;
    const int w    = tid >> 6;
    if (lane < Sn) ws[w][lane] = 0.0f;     // same-wave ordering: no barrier needed

    if (blockIdx.x < OBLK) {
        // -------- onset path: softmax over B, 4 consecutive columns per thread --------
        const int cq = blockIdx.x * BDIM + tid;
        float on = 0.0f;
        int   s  = Sn - 1;                  // tail lanes: contiguity-safe string
        if (cq < CQN) {
            s = (cq * CPT) / Tn;            // quad never crosses string (2000 % 4 == 0)
            const float4* oxp = (const float4*)ox + cq;
            const float4* otp = (const float4*)ot + cq;
            float M[4], S_[4], ts[4], txs[4];
            #pragma unroll
            for (int j = 0; j < 4; ++j) { M[j] = -INFINITY; S_[j] = 0.0f; ts[j] = 0.0f; txs[j] = 0.0f; }
            for (int b0 = 0; b0 < Bn; b0 += 8) {
                float4 xv[8], tv[8];
                #pragma unroll
                for (int k = 0; k < 8; ++k) xv[k] = oxp[(long)(b0 + k) * (COLS / 4)];
                #pragma unroll
                for (int k = 0; k < 8; ++k) tv[k] = otp[(long)(b0 + k) * (COLS / 4)];
                #pragma unroll
                for (int j = 0; j < 4; ++j) {
                    float cm = -INFINITY;
                    #pragma unroll
                    for (int k = 0; k < 8; ++k) cm = fmaxf(cm, comp(xv[k], j));
                    float cs = 0.0f;
                    #pragma unroll
                    for (int k = 0; k < 8; ++k) cs += __expf(comp(xv[k], j) - cm);
                    const float nm = fmaxf(M[j], cm);
                    S_[j] = S_[j] * __expf(M[j] - nm) + cs * __expf(cm - nm);  // exp(-inf)=0 first iter
                    M[j]  = nm;
                    #pragma unroll
                    for (int k = 0; k < 8; ++k) {
                        const float t = comp(tv[k], j);
                        ts[j]  += t;
                        txs[j] += t * comp(xv[k], j);
                    }
                }
            }
            #pragma unroll
            for (int j = 0; j < 4; ++j) on += ts[j] * (M[j] + __logf(S_[j])) - txs[j];
        }
        seg_reduce_add(ws[w], s, on, lane);
        __syncthreads();
        if (tid < Sn)
            po[tid * OPAD + blockIdx.x] = ws[0][tid] + ws[1][tid] + ws[2][tid] + ws[3][tid];
    } else {
        // -------- fret path: CE over 25 classes, 4 consecutive rows per thread --------
        const int  fb = blockIdx.x - OBLK;
        const long q  = (long)fb * BDIM + tid;          // row-quad index
        // 25 independent float4 loads -> 400 B/lane in flight (MLP fix).
        const float4* src = x4 + q * 25;
        float v[RPT * Cn];                               // static indices only
        #pragma unroll
        for (int c = 0; c < 25; ++c) {
            const float4 t = src[c];
            v[4 * c + 0] = t.x; v[4 * c + 1] = t.y; v[4 * c + 2] = t.z; v[4 * c + 3] = t.w;
        }
        const int4 t4 = tgt4[q];                         // coalesced 16B target load
        float acc = 0.0f;
        #pragma unroll
        for (int r = 0; r < RPT; ++r) {
            const int tc = (r == 0) ? t4.x : (r == 1) ? t4.y : (r == 2) ? t4.z : t4.w;
            float m = -INFINITY, xt = 0.0f;
            #pragma unroll
            for (int c = 0; c < Cn; ++c) {
                const float e = v[r * Cn + c];
                m  = fmaxf(m, e);
                xt = (c == tc) ? e : xt;                 // select, no runtime reg index
            }
            float ssum = 0.0f;
            #pragma unroll
            for (int c = 0; c < Cn; ++c) ssum += __expf(v[r * Cn + c] - m);
            acc += m + __logf(ssum) - xt;
        }
        const int s = (int)((q * RPT) / Tn) % Sn;        // quad single-string (2000%4==0)
        seg_reduce_add(ws[w], s, acc, lane);
        __syncthreads();
        if (tid < Sn)
            pf[tid * FPAD + fb] = ws[0][tid] + ws[1][tid] + ws[2][tid] + ws[3][tid];
    }
}

__global__ __launch_bounds__(1024) void finish_kernel(const float* __restrict__ pf,
                                                      const float* __restrict__ po,
                                                      float* __restrict__ out) {
    __shared__ float acc[2 * Sn];
    const int tid  = threadIdx.x;
    const int lane = tid & 63;
    if (tid < 2 * Sn) acc[tid] = 0.0f;
    __syncthreads();

    // ---- fret partials: 6 independent coalesced sweeps (750 < 1024: one load each) ----
    float fs[Sn];
    #pragma unroll
    for (int s = 0; s < Sn; ++s) {
        float v = 0.0f;
        for (int i = tid; i < FBLK; i += 1024) v += pf[s * FPAD + i];
        fs[s] = v;
    }
    #pragma unroll
    for (int off = 32; off; off >>= 1) {
        #pragma unroll
        for (int s = 0; s < Sn; ++s) fs[s] += __shfl_xor(fs[s], off, 64);
    }
    if (lane == 0) {
        #pragma unroll
        for (int s = 0; s < Sn; ++s) atomicAdd(&acc[s], fs[s]);
    }

    // ---- onset partials: wave w sums string w (12 entries) ----
    const int wv = tid >> 6;
    if (wv < Sn) {
        float v = (lane < OBLK) ? po[wv * OPAD + lane] : 0.0f;
        #pragma unroll
        for (int off = 32; off; off >>= 1) v += __shfl_xor(v, off, 64);
        if (lane == 0) acc[Sn + wv] = v;
    }
    __syncthreads();

    if (tid == 0) {
        float fret = 0.0f, on = 0.0f, fsv[Sn], osv[Sn];
        #pragma unroll
        for (int s = 0; s < Sn; ++s) {
            fsv[s] = acc[s] * (1.0f / Bn);              // mean over batch
            osv[s] = acc[Sn + s];
            fret += fsv[s];
            on   += osv[s];
        }
        out[0] = 0.5f * fret + 0.5f * on;               // WEIGHT_FRET_ONSET = 0.5
        out[1] = fret;
        out[2] = on;
        #pragma unroll
        for (int s = 0; s < Sn; ++s) { out[3 + s] = fsv[s]; out[9 + s] = osv[s]; }
    }
}

extern "C" void kernel_launch(void* const* d_in, const int* in_sizes, int n_in,
                              void* d_out, int out_size, void* d_ws, size_t ws_size,
                              hipStream_t stream) {
    const float* output_fret  = (const float*)d_in[0];
    const int*   target_fret  = (const int*)d_in[1];
    const float* output_onset = (const float*)d_in[2];
    const float* target_onset = (const float*)d_in[3];
    float* pf  = (float*)d_ws;                 // [Sn][FPAD]
    float* po  = pf + Sn * FPAD;               // [Sn][OPAD]
    float* out = (float*)d_out;

    main_kernel<<<GRID, BDIM, 0, stream>>>((const float4*)output_fret,
                                           (const int4*)target_fret,
                                           output_onset, target_onset, pf, po);
    finish_kernel<<<1, 1024, 0, stream>>>(pf, po, out);
}